// Round 10
// baseline (571.516 us; speedup 1.0000x reference)
//
#include <hip/hip_runtime.h>
#include <hip/hip_bf16.h>
#include <math.h>

#define NN 8192
#define DD 512
#define INV_T 14.285714285714286f   // 1/0.07 ; also the logits_max (diagonal) value

typedef __attribute__((ext_vector_type(8))) short s16x8;  // 8 bf16 = 4 VGPRs
typedef __attribute__((ext_vector_type(4))) float f32x4;
typedef __attribute__((ext_vector_type(4))) int   i32x4;

__device__ __forceinline__ unsigned short f32_to_bf16(float f) {
  unsigned int u = __float_as_uint(f);
  u += 0x7FFFu + ((u >> 16) & 1u);   // round-to-nearest-even
  return (unsigned short)(u >> 16);
}

__device__ __forceinline__ void async16(const void* g, void* l) {
  // 16B-wide global->LDS DMA; LDS dest must be wave-uniform base + lane*16
  __builtin_amdgcn_global_load_lds((__attribute__((address_space(1))) void*)(void*)g,
                                   (__attribute__((address_space(3))) void*)l,
                                   16, 0, 0);
}

// ---------------- Kernel A: normalize rows, emit bf16 ----------------
__global__ __launch_bounds__(256) void normalize_kernel(const float* __restrict__ f,
                                                        unsigned short* __restrict__ fnb) {
  const int wave = threadIdx.x >> 6;
  const int lane = threadIdx.x & 63;
  const int row  = blockIdx.x * 4 + wave;
  const float* src = f + (size_t)row * DD + lane * 8;
  float4 v0 = *(const float4*)src;
  float4 v1 = *(const float4*)(src + 4);
  float ss = v0.x*v0.x + v0.y*v0.y + v0.z*v0.z + v0.w*v0.w
           + v1.x*v1.x + v1.y*v1.y + v1.z*v1.z + v1.w*v1.w;
  #pragma unroll
  for (int o = 32; o; o >>= 1) ss += __shfl_xor(ss, o);
  const float r = 1.0f / fmaxf(sqrtf(ss), 1e-8f);
  ushort4 a, b;
  a.x = f32_to_bf16(v0.x * r); a.y = f32_to_bf16(v0.y * r);
  a.z = f32_to_bf16(v0.z * r); a.w = f32_to_bf16(v0.w * r);
  b.x = f32_to_bf16(v1.x * r); b.y = f32_to_bf16(v1.y * r);
  b.z = f32_to_bf16(v1.z * r); b.w = f32_to_bf16(v1.w * r);
  unsigned short* dst = fnb + (size_t)row * DD + lane * 8;
  *(ushort4*)dst = a;
  *(ushort4*)(dst + 4) = b;
}

// ---------------- Kernel B: split-K-loop fused kernel ----------------
// 128x128 tile per block, 4 waves each 64x64. BK=64 (16x16x32 MFMA, 2 k-steps
// per staged tile). ROW-SPLIT: loop1 computes acc for mt 0,1 (rows wm*64+0..31);
// loop2 computes mt 2,3 AND carries half the epilogue's mask stream interleaved
// between its barriers. Loads cannot be moved across s_barrier, so the compiler
// cannot sink the mask loads to their consumers (the R5 failure); the iter-k
// barrier also guarantees iter-k mask loads have landed before their iter-k+1
// FMA drain. B-columns use R6/R9's permutation (lane c16 owns sim cols
// 4*c16..4*c16+3 == one int4 of mask). LDS accumulation for sums; one batch of
// global atomics at the end.
__global__ __launch_bounds__(256, 2) void fused_kernel(const unsigned short* __restrict__ fnb,
                                                       const int* __restrict__ posm,
                                                       const int* __restrict__ negm,
                                                       float* __restrict__ Spos,
                                                       float* __restrict__ Sneg,
                                                       float* __restrict__ Pcnt) {
  // decode compact triangular block id -> (bi, bj), bi <= bj, 64x64 block grid
  const int bid = blockIdx.x;
  int bi = (int)(64.5 - sqrt(64.5 * 64.5 - 2.0 * (double)bid));
  while (64 * bi - bi * (bi - 1) / 2 > bid) --bi;
  while (64 * (bi + 1) - (bi + 1) * bi / 2 <= bid) ++bi;
  const int bj = bi + (bid - (64 * bi - bi * (bi - 1) / 2));
  const int I = bi * 128;
  const int J = bj * 128;
  const bool offdiag = (bi != bj);

  const int tid  = threadIdx.x;
  const int wave = tid >> 6;
  const int lane = tid & 63;
  const int wm = wave >> 1;            // 0..1 row half
  const int wn = wave & 1;             // 0..1 col half
  const int q   = lane >> 4;           // 0..3
  const int c16 = lane & 15;           // 0..15

  __shared__ alignas(16) unsigned short lA[64 * 64];    // 8 KB: 64 rows x BK=64
  __shared__ alignas(16) unsigned short lB[128 * 64];   // 16 KB
  __shared__ float sacc[2][128][3];                     // [panel][row][Spos,Sneg,Pcnt]
  for (int t = tid; t < 2 * 128 * 3; t += 256) ((float*)sacc)[t] = 0.f;

  f32x4 acc[4][4];
  const f32x4 z4 = {0.f, 0.f, 0.f, 0.f};
  #pragma unroll
  for (int mt = 0; mt < 4; ++mt)
    #pragma unroll
    for (int nt = 0; nt < 4; ++nt) acc[mt][nt] = z4;

  const bool hasdiag = (bi == bj) && (wm == wn);
  const int cb = wn * 64 + 4 * c16;    // local col base (this lane's int4)

  // ---- mask pipeline state ----
  i32x4 dP[2][4], dN[2][4];            // direct batches, slot = mt&1
  i32x4 tP[4][2], tN[4][2];            // transposed: [nt][m2]
  float ts[4] = {0,0,0,0}, tn[4] = {0,0,0,0}, tp[4] = {0,0,0,0};

  auto dIssue = [&](int m) {
    const int rl = wm * 64 + m * 16 + q * 4;
    #pragma unroll
    for (int r = 0; r < 4; ++r) {
      const size_t off = (size_t)(I + rl + r) * NN + J + cb;
      dP[m & 1][r] = __builtin_nontemporal_load((const i32x4*)(posm + off));
      dN[m & 1][r] = __builtin_nontemporal_load((const i32x4*)(negm + off));
    }
  };
  auto dDrain = [&](int m) {
    const int rl = wm * 64 + m * 16 + q * 4;
    #pragma unroll
    for (int r = 0; r < 4; ++r) {
      float dsp = 0.f, dsn = 0.f, dpc = 0.f;
      #pragma unroll
      for (int nt = 0; nt < 4; ++nt) {
        float pf = (float)dP[m & 1][r][nt];
        float nf = (float)dN[m & 1][r][nt];
        if (hasdiag && (rl + r == cb + nt)) { pf = 0.f; nf = 0.f; }  // self-contrast diag
        const float e = acc[m][nt][r];
        dsp = fmaf(e, pf, dsp);
        dsn = fmaf(e, nf, dsn);
        dpc += pf;
      }
      #pragma unroll
      for (int o = 1; o <= 8; o <<= 1) {
        dsp += __shfl_xor(dsp, o);
        dsn += __shfl_xor(dsn, o);
        dpc += __shfl_xor(dpc, o);
      }
      if (c16 == 0) {   // LDS atomics: lgkmcnt only
        atomicAdd(&sacc[0][rl + r][0], dsp);
        atomicAdd(&sacc[0][rl + r][1], dsn);
        atomicAdd(&sacc[0][rl + r][2], dpc);
      }
    }
  };
  auto tIssue = [&](int nt, int mh) {
    #pragma unroll
    for (int m2 = 0; m2 < 2; ++m2) {
      const size_t off = (size_t)(J + cb + nt) * NN + I + wm * 64 + (mh * 2 + m2) * 16 + q * 4;
      tP[nt][m2] = __builtin_nontemporal_load((const i32x4*)(posm + off));
      tN[nt][m2] = __builtin_nontemporal_load((const i32x4*)(negm + off));
    }
  };
  auto tDrain = [&](int nt, int mh) {
    #pragma unroll
    for (int m2 = 0; m2 < 2; ++m2) {
      const int m = mh * 2 + m2;
      #pragma unroll
      for (int r = 0; r < 4; ++r) {
        const float e  = acc[m][nt][r];
        const float pf = (float)tP[nt][m2][r];
        ts[nt] = fmaf(e, pf, ts[nt]);
        tn[nt] = fmaf(e, (float)tN[nt][m2][r], tn[nt]);
        tp[nt] += pf;
      }
    }
  };

  // staging for half h, K-chunk kk (both loops stage lA-half + full lB)
  auto stage = [&](int h, int kk) {
    const int k0 = kk * 64;
    #pragma unroll
    for (int c = 0; c < 2; ++c) {      // lA: 512 chunks
      const int fidx = tid + c * 256;
      const int L = fidx >> 3, p = fidx & 7;
      const int cs = p ^ (L & 7);      // chunk XOR swizzle (global side)
      async16(fnb + (size_t)(I + (L >> 5) * 64 + h * 32 + (L & 31)) * DD + k0 + cs * 8,
              (char*)lA + fidx * 16);
    }
    #pragma unroll
    for (int c = 0; c < 4; ++c) {      // lB: 1024 chunks, row-permuted
      const int fidx = tid + c * 256;
      const int L = fidx >> 3, p = fidx & 7;
      const int cs = p ^ (L & 7);
      async16(fnb + (size_t)(J + 4 * (L & 31) + (L >> 5)) * DD + k0 + cs * 8,
              (char*)lB + fidx * 16);
    }
  };
  // 16 MFMA for half h from staged tiles
  auto gemmstep = [&](int h) {
    #pragma unroll
    for (int ks = 0; ks < 2; ++ks) {
      s16x8 aF[2], bF[4];
      #pragma unroll
      for (int mt2 = 0; mt2 < 2; ++mt2) {
        const int La = wm * 32 + mt2 * 16 + c16;
        const int cc = (ks * 4 + q) ^ (La & 7);
        aF[mt2] = *(const s16x8*)((const char*)lA + La * 128 + cc * 16);
      }
      #pragma unroll
      for (int t = 0; t < 4; ++t) {
        const int Lb = wn * 16 + c16 + 32 * t;   // global row J + 4*c16 + t (permuted)
        const int cc = (ks * 4 + q) ^ (Lb & 7);
        bF[t] = *(const s16x8*)((const char*)lB + Lb * 128 + cc * 16);
      }
      #pragma unroll
      for (int mt2 = 0; mt2 < 2; ++mt2)
        #pragma unroll
        for (int nt = 0; nt < 4; ++nt)
          acc[h * 2 + mt2][nt] =
              __builtin_amdgcn_mfma_f32_16x16x32_bf16(aF[mt2], bF[nt], acc[h * 2 + mt2][nt], 0, 0, 0);
    }
  };

  // ---- loop 1: rows mt 0,1 ----
  for (int kk = 0; kk < 8; ++kk) {
    stage(0, kk);
    __syncthreads();
    gemmstep(0);
    __syncthreads();
  }
  // convert half1 to e
  #pragma unroll
  for (int mt = 0; mt < 2; ++mt)
    #pragma unroll
    for (int nt = 0; nt < 4; ++nt)
      #pragma unroll
      for (int r = 0; r < 4; ++r)
        acc[mt][nt][r] = __expf(acc[mt][nt][r] * INV_T - INV_T);

  // ---- loop 2: rows mt 2,3 + barrier-pinned mask interleave for half1 ----
  #pragma unroll
  for (int kk = 0; kk < 8; ++kk) {
    stage(1, kk);
    if (kk == 0) dIssue(0);
    if (kk == 1) dIssue(1);
    if (kk == 2 && offdiag) { tIssue(0, 0); tIssue(1, 0); }
    if (kk == 3 && offdiag) { tIssue(2, 0); tIssue(3, 0); }
    __syncthreads();                   // drains staging AND mask loads
    gemmstep(1);
    if (kk == 1) dDrain(0);
    if (kk == 2) dDrain(1);
    if (kk == 3 && offdiag) { tDrain(0, 0); tDrain(1, 0); }
    if (kk == 4 && offdiag) { tDrain(2, 0); tDrain(3, 0); }
    __syncthreads();
  }
  // convert half2 to e
  #pragma unroll
  for (int mt = 2; mt < 4; ++mt)
    #pragma unroll
    for (int nt = 0; nt < 4; ++nt)
      #pragma unroll
      for (int r = 0; r < 4; ++r)
        acc[mt][nt][r] = __expf(acc[mt][nt][r] * INV_T - INV_T);

  // ---- remaining (serial) half of the mask stream ----
  dIssue(2); dIssue(3);
  dDrain(2); dDrain(3);
  if (offdiag) {
    tIssue(0, 1); tIssue(1, 1);
    tDrain(0, 1); tDrain(1, 1);
    tIssue(2, 1); tIssue(3, 1);
    tDrain(2, 1); tDrain(3, 1);
    #pragma unroll
    for (int nt = 0; nt < 4; ++nt) {
      float a = ts[nt], b = tn[nt], p = tp[nt];
      a += __shfl_xor(a, 16); a += __shfl_xor(a, 32);
      b += __shfl_xor(b, 16); b += __shfl_xor(b, 32);
      p += __shfl_xor(p, 16); p += __shfl_xor(p, 32);
      if (q == 0) {
        atomicAdd(&sacc[1][cb + nt][0], a);
        atomicAdd(&sacc[1][cb + nt][1], b);
        atomicAdd(&sacc[1][cb + nt][2], p);
      }
    }
  }

  __syncthreads();

  // one batch of global atomics at the very end; nothing waits on them
  const int r = tid & 127;
  if (tid < 128) {
    atomicAdd(&Spos[I + r], sacc[0][r][0]);
    atomicAdd(&Sneg[I + r], sacc[0][r][1]);
    atomicAdd(&Pcnt[I + r], sacc[0][r][2]);
  } else if (offdiag) {
    atomicAdd(&Spos[J + r], sacc[1][r][0]);
    atomicAdd(&Sneg[J + r], sacc[1][r][1]);
    atomicAdd(&Pcnt[J + r], sacc[1][r][2]);
  }
}

// ---------------- Kernel C: finalize ----------------
__global__ __launch_bounds__(256) void finalize_kernel(const float* __restrict__ Spos,
                                                       const float* __restrict__ Sneg,
                                                       const float* __restrict__ Pcnt,
                                                       float* __restrict__ out) {
  float local = 0.f;
  for (int i = threadIdx.x; i < NN; i += 256) {
    const float sp = Spos[i], sn = Sneg[i], pc = Pcnt[i];
    const float card = (pc == 0.f) ? 1.f : pc;
    local += (logf(sn) * pc - sp) / card;
  }
  #pragma unroll
  for (int o = 32; o; o >>= 1) local += __shfl_xor(local, o);
  __shared__ float red[4];
  if ((threadIdx.x & 63) == 0) red[threadIdx.x >> 6] = local;
  __syncthreads();
  if (threadIdx.x == 0)
    out[0] = (red[0] + red[1] + red[2] + red[3]) * (1.0f / (float)NN);
}

extern "C" void kernel_launch(void* const* d_in, const int* in_sizes, int n_in,
                              void* d_out, int out_size, void* d_ws, size_t ws_size,
                              hipStream_t stream) {
  const float* feat = (const float*)d_in[0];
  const int* posm   = (const int*)d_in[1];
  const int* negm   = (const int*)d_in[2];
  float* out = (float*)d_out;

  char* ws = (char*)d_ws;
  unsigned short* fnb = (unsigned short*)ws;                 // 8 MB
  float* Spos = (float*)(ws + (size_t)8 * 1024 * 1024);
  float* Sneg = Spos + NN;
  float* Pcnt = Sneg + NN;

  hipMemsetAsync(Spos, 0, 3 * NN * sizeof(float), stream);
  normalize_kernel<<<NN / 4, 256, 0, stream>>>(feat, fnb);
  fused_kernel<<<2080, 256, 0, stream>>>(fnb, posm, negm, Spos, Sneg, Pcnt);
  finalize_kernel<<<1, 256, 0, stream>>>(Spos, Sneg, Pcnt, out);
}